// Round 1
// baseline (108.938 us; speedup 1.0000x reference)
//
#include <hip/hip_runtime.h>

#define NB 8
#define LQ 4096
#define SK 4096
#define NH 8
#define DD 64
#define NPAIR (NB*NH)        // 64 (n,h) pairs
#define KVSZ (DD*DD + DD)    // 4160: 64x64 KV + 64 Ksum

__device__ __forceinline__ float fmap(float x) {
    // elu(x)+1 : x>0 ? x+1 : exp(x)
    return x > 0.f ? x + 1.f : __expf(x);
}

// ---------------- Phase 1: partial KV = sum_s K[s]⊗V[s], Ksum = sum_s K[s] --------
__global__ __launch_bounds__(256) void kv_partial_kernel(
    const float* __restrict__ K, const float* __restrict__ V,
    const float* __restrict__ kvm, float* __restrict__ partial,
    int CH, int SC)
{
    int bx = blockIdx.x;
    int chunk = bx % CH;
    int pair  = bx / CH;
    int n = pair >> 3, h = pair & 7;
    int t = threadIdx.x;
    int d  = t & 63;      // lane = d index -> conflict-free K column reads
    int vg = t >> 6;      // wave id = v-quarter

    __shared__ float Kl[64][64];
    __shared__ float Vl[64][64];

    float acc[16];
#pragma unroll
    for (int j = 0; j < 16; ++j) acc[j] = 0.f;
    float ksum = 0.f;

    int s0 = chunk * SC;
    for (int s = s0; s < s0 + SC; s += 64) {
        // cooperative load of 64 rows x 64 cols of K and V (coalesced float4)
#pragma unroll
        for (int k = 0; k < 4; ++k) {
            int f = t + 256 * k;
            int r = f >> 4, c = f & 15;
            size_t base = ((size_t)((n * SK + s + r) * NH + h)) * DD + c * 4;
            float m = kvm[n * SK + s + r];
            float4 kf = *(const float4*)(K + base);
            float4 vf = *(const float4*)(V + base);
            kf.x = fmap(kf.x) * m; kf.y = fmap(kf.y) * m;
            kf.z = fmap(kf.z) * m; kf.w = fmap(kf.w) * m;
            vf.x *= m; vf.y *= m; vf.z *= m; vf.w *= m;
            *(float4*)&Kl[r][c * 4] = kf;
            *(float4*)&Vl[r][c * 4] = vf;
        }
        __syncthreads();
#pragma unroll 4
        for (int r = 0; r < 64; ++r) {
            float kd = Kl[r][d];               // lanes consecutive -> no conflict
            if (vg == 0) ksum += kd;           // wave-uniform branch
            const float4* vrow = (const float4*)&Vl[r][vg * 16];  // broadcast
            float4 v0 = vrow[0], v1 = vrow[1], v2 = vrow[2], v3 = vrow[3];
            acc[0]  += kd * v0.x; acc[1]  += kd * v0.y; acc[2]  += kd * v0.z; acc[3]  += kd * v0.w;
            acc[4]  += kd * v1.x; acc[5]  += kd * v1.y; acc[6]  += kd * v1.z; acc[7]  += kd * v1.w;
            acc[8]  += kd * v2.x; acc[9]  += kd * v2.y; acc[10] += kd * v2.z; acc[11] += kd * v2.w;
            acc[12] += kd * v3.x; acc[13] += kd * v3.y; acc[14] += kd * v3.z; acc[15] += kd * v3.w;
        }
        __syncthreads();
    }
    float* dst = partial + ((size_t)chunk * NPAIR + pair) * KVSZ;
    float* o = dst + d * 64 + vg * 16;
    *(float4*)&o[0]  = make_float4(acc[0],  acc[1],  acc[2],  acc[3]);
    *(float4*)&o[4]  = make_float4(acc[4],  acc[5],  acc[6],  acc[7]);
    *(float4*)&o[8]  = make_float4(acc[8],  acc[9],  acc[10], acc[11]);
    *(float4*)&o[12] = make_float4(acc[12], acc[13], acc[14], acc[15]);
    if (vg == 0) dst[4096 + d] = ksum;
}

// ---------------- Phase 1b: reduce partials over chunks -----------------
__global__ __launch_bounds__(256) void kv_reduce_kernel(
    const float* __restrict__ partial, float* __restrict__ kvf, int CH)
{
    int i = blockIdx.x * 256 + threadIdx.x;
    if (i >= NPAIR * KVSZ) return;
    float s = 0.f;
    for (int c = 0; c < CH; ++c) s += partial[(size_t)c * NPAIR * KVSZ + i];
    kvf[i] = s;
}

// ---------------- Phase 2: out = (q·KV) / (q·Ksum + eps) -----------------
__global__ __launch_bounds__(256) void attn_out_kernel(
    const float* __restrict__ Q, const float* __restrict__ qm,
    const float* __restrict__ kvf, float* __restrict__ out)
{
    int bx = blockIdx.x;
    int pair = bx & 63;
    int tile = bx >> 6;          // 64 rows per tile
    int n = pair >> 3, h = pair & 7;
    int t = threadIdx.x;
    int r  = t >> 2;             // local row 0..63
    int qg = t & 3;              // v-quarter (16 cols)

    __shared__ float Ql[64][65];   // +1 pad -> stride-65 row reads conflict-free
    __shared__ float KVl[KVSZ];

    // load KV + Ksum for this (n,h)
    for (int k = 0; k < 17; ++k) {
        int i = t + 256 * k;
        if (i < KVSZ) KVl[i] = kvf[(size_t)pair * KVSZ + i];
    }
    // load 64 Q rows (coalesced float4), apply feature map + mask
    int l0 = tile * 64;
#pragma unroll
    for (int k = 0; k < 4; ++k) {
        int f = t + 256 * k;
        int rr = f >> 4, c = f & 15;
        float m = qm[n * LQ + l0 + rr];
        float4 qf = *(const float4*)(Q + ((size_t)((n * LQ + l0 + rr) * NH + h)) * DD + c * 4);
        Ql[rr][c * 4 + 0] = fmap(qf.x) * m;
        Ql[rr][c * 4 + 1] = fmap(qf.y) * m;
        Ql[rr][c * 4 + 2] = fmap(qf.z) * m;
        Ql[rr][c * 4 + 3] = fmap(qf.w) * m;
    }
    __syncthreads();

    float acc[16];
#pragma unroll
    for (int j = 0; j < 16; ++j) acc[j] = 0.f;
    float den = 0.f;

#pragma unroll 4
    for (int dd = 0; dd < 64; ++dd) {
        float qd = Ql[r][dd];                       // 16 banks, 4-lane broadcast
        den += qd * KVl[4096 + dd];                 // broadcast
        const float4* kvrow = (const float4*)&KVl[dd * 64 + qg * 16];  // <=2-way
        float4 v0 = kvrow[0], v1 = kvrow[1], v2 = kvrow[2], v3 = kvrow[3];
        acc[0]  += qd * v0.x; acc[1]  += qd * v0.y; acc[2]  += qd * v0.z; acc[3]  += qd * v0.w;
        acc[4]  += qd * v1.x; acc[5]  += qd * v1.y; acc[6]  += qd * v1.z; acc[7]  += qd * v1.w;
        acc[8]  += qd * v2.x; acc[9]  += qd * v2.y; acc[10] += qd * v2.z; acc[11] += qd * v2.w;
        acc[12] += qd * v3.x; acc[13] += qd * v3.y; acc[14] += qd * v3.z; acc[15] += qd * v3.w;
    }
    float z = 1.f / (den + 1e-6f);
    float* orow = out + ((size_t)((n * LQ + l0 + r) * NH + h)) * DD + qg * 16;
    *(float4*)&orow[0]  = make_float4(acc[0]  * z, acc[1]  * z, acc[2]  * z, acc[3]  * z);
    *(float4*)&orow[4]  = make_float4(acc[4]  * z, acc[5]  * z, acc[6]  * z, acc[7]  * z);
    *(float4*)&orow[8]  = make_float4(acc[8]  * z, acc[9]  * z, acc[10] * z, acc[11] * z);
    *(float4*)&orow[12] = make_float4(acc[12] * z, acc[13] * z, acc[14] * z, acc[15] * z);
}

extern "C" void kernel_launch(void* const* d_in, const int* in_sizes, int n_in,
                              void* d_out, int out_size, void* d_ws, size_t ws_size,
                              hipStream_t stream) {
    const float* Q   = (const float*)d_in[0];
    const float* K   = (const float*)d_in[1];
    const float* V   = (const float*)d_in[2];
    const float* qm  = (const float*)d_in[3];
    const float* kvm = (const float*)d_in[4];
    float* out = (float*)d_out;

    // pick chunk count that fits the workspace: (CH partials + 1 final) * 64 * 4160 floats
    int CH = 8;
    while (CH > 1 && (size_t)(CH + 1) * NPAIR * KVSZ * sizeof(float) > ws_size) CH >>= 1;
    int SC = SK / CH;

    float* partial = (float*)d_ws;
    float* kvf = partial + (size_t)CH * NPAIR * KVSZ;

    kv_partial_kernel<<<dim3(NPAIR * CH), dim3(256), 0, stream>>>(K, V, kvm, partial, CH, SC);
    kv_reduce_kernel<<<dim3((NPAIR * KVSZ + 255) / 256), dim3(256), 0, stream>>>(partial, kvf, CH);
    attn_out_kernel<<<dim3(NPAIR * 64), dim3(256), 0, stream>>>(Q, qm, kvf, out);
}

// Round 2
// 100.264 us; speedup vs baseline: 1.0865x; 1.0865x over previous
//
#include <hip/hip_runtime.h>

#define NB 8
#define LQ 4096
#define SK 4096
#define NH 8
#define DD 64
#define NPAIR (NB*NH)        // 64 (n,h) pairs
#define KVSZ (DD*DD + DD)    // 4160: 64x64 KV + 64 Ksum

__device__ __forceinline__ float fmap(float x) {
    // elu(x)+1 : x>0 ? x+1 : exp(x)
    return x > 0.f ? x + 1.f : __expf(x);
}

// ---------------- Phase 1: partial KV = sum_s K[s]⊗V[s], Ksum = sum_s K[s] --------
// Each thread owns a 4(d)x4(v) register patch: per K-row only 2 ds_read_b128
// feed 16 FMAs (vs 5 LDS instrs before). Ksum via separate conflict-free
// column-sum pass (lane->consecutive cols, 2 lanes/bank = free).
__global__ __launch_bounds__(256) void kv_partial_kernel(
    const float* __restrict__ K, const float* __restrict__ V,
    const float* __restrict__ kvm, float* __restrict__ partial,
    int CH, int SC)
{
    int bx = blockIdx.x;
    int chunk = bx % CH;
    int pair  = bx / CH;
    int n = pair >> 3, h = pair & 7;
    int t = threadIdx.x;
    int td = t >> 4;      // d-block: rows td*4..td*4+3
    int tv = t & 15;      // v-block: cols tv*4..tv*4+3
    int col = t & 63;     // for ksum pass
    int q   = t >> 6;

    __shared__ float Kl[64][64];
    __shared__ float Vl[64][64];
    __shared__ float Ks[4][64];

    float acc[4][4] = {};
    float ksum = 0.f;

    int s0 = chunk * SC;
    for (int s = s0; s < s0 + SC; s += 64) {
        // cooperative load of 64 rows x 64 cols of K and V (coalesced float4)
#pragma unroll
        for (int k = 0; k < 4; ++k) {
            int f = t + 256 * k;
            int r = f >> 4, c = f & 15;
            size_t base = ((size_t)((n * SK + s + r) * NH + h)) * DD + c * 4;
            float m = kvm[n * SK + s + r];
            float4 kf = *(const float4*)(K + base);
            float4 vf = *(const float4*)(V + base);
            kf.x = fmap(kf.x) * m; kf.y = fmap(kf.y) * m;
            kf.z = fmap(kf.z) * m; kf.w = fmap(kf.w) * m;
            vf.x *= m; vf.y *= m; vf.z *= m; vf.w *= m;
            *(float4*)&Kl[r][c * 4] = kf;
            *(float4*)&Vl[r][c * 4] = vf;
        }
        __syncthreads();

        // ksum partial: quarter q sums 16 rows of column `col`
#pragma unroll
        for (int i = 0; i < 16; ++i) ksum += Kl[q * 16 + i][col];

        // main rank-1 accumulation: 2 b128 reads -> 16 FMA
#pragma unroll 8
        for (int r = 0; r < 64; ++r) {
            float4 kf = *(const float4*)&Kl[r][td * 4];  // 4 distinct addrs, 16-way bcast
            float4 vf = *(const float4*)&Vl[r][tv * 4];  // 256B contiguous, 4-way bcast
            acc[0][0] += kf.x * vf.x; acc[0][1] += kf.x * vf.y; acc[0][2] += kf.x * vf.z; acc[0][3] += kf.x * vf.w;
            acc[1][0] += kf.y * vf.x; acc[1][1] += kf.y * vf.y; acc[1][2] += kf.y * vf.z; acc[1][3] += kf.y * vf.w;
            acc[2][0] += kf.z * vf.x; acc[2][1] += kf.z * vf.y; acc[2][2] += kf.z * vf.z; acc[2][3] += kf.z * vf.w;
            acc[3][0] += kf.w * vf.x; acc[3][1] += kf.w * vf.y; acc[3][2] += kf.w * vf.z; acc[3][3] += kf.w * vf.w;
        }
        __syncthreads();
    }

    float* dst = partial + ((size_t)chunk * NPAIR + pair) * KVSZ;
#pragma unroll
    for (int i = 0; i < 4; ++i) {
        *(float4*)&dst[(td * 4 + i) * 64 + tv * 4] =
            make_float4(acc[i][0], acc[i][1], acc[i][2], acc[i][3]);
    }
    Ks[q][col] = ksum;
    __syncthreads();
    if (t < 64) dst[4096 + t] = Ks[0][t] + Ks[1][t] + Ks[2][t] + Ks[3][t];
}

// ---------------- Phase 1b: reduce partials over chunks -----------------
__global__ __launch_bounds__(256) void kv_reduce_kernel(
    const float* __restrict__ partial, float* __restrict__ kvf, int CH)
{
    int i = blockIdx.x * 256 + threadIdx.x;
    if (i >= NPAIR * KVSZ) return;
    float s = 0.f;
    for (int c = 0; c < CH; ++c) s += partial[(size_t)c * NPAIR * KVSZ + i];
    kvf[i] = s;
}

// ---------------- Phase 2: out = (q·KV) / (q·Ksum + eps) -----------------
__global__ __launch_bounds__(256) void attn_out_kernel(
    const float* __restrict__ Q, const float* __restrict__ qm,
    const float* __restrict__ kvf, float* __restrict__ out)
{
    int bx = blockIdx.x;
    int pair = bx & 63;
    int tile = bx >> 6;          // 64 rows per tile
    int n = pair >> 3, h = pair & 7;
    int t = threadIdx.x;
    int r  = t >> 2;             // local row 0..63
    int qg = t & 3;              // v-quarter (16 cols)

    __shared__ float Ql[64][65];   // +1 pad -> stride-65 row reads conflict-free
    __shared__ float KVl[KVSZ];

    // load KV + Ksum for this (n,h)
    for (int k = 0; k < 17; ++k) {
        int i = t + 256 * k;
        if (i < KVSZ) KVl[i] = kvf[(size_t)pair * KVSZ + i];
    }
    // load 64 Q rows (coalesced float4), apply feature map + mask
    int l0 = tile * 64;
#pragma unroll
    for (int k = 0; k < 4; ++k) {
        int f = t + 256 * k;
        int rr = f >> 4, c = f & 15;
        float m = qm[n * LQ + l0 + rr];
        float4 qf = *(const float4*)(Q + ((size_t)((n * LQ + l0 + rr) * NH + h)) * DD + c * 4);
        Ql[rr][c * 4 + 0] = fmap(qf.x) * m;
        Ql[rr][c * 4 + 1] = fmap(qf.y) * m;
        Ql[rr][c * 4 + 2] = fmap(qf.z) * m;
        Ql[rr][c * 4 + 3] = fmap(qf.w) * m;
    }
    __syncthreads();

    float acc[16];
#pragma unroll
    for (int j = 0; j < 16; ++j) acc[j] = 0.f;
    float den = 0.f;

#pragma unroll 4
    for (int dd = 0; dd < 64; ++dd) {
        float qd = Ql[r][dd];                       // 16 banks, 4-lane broadcast
        den += qd * KVl[4096 + dd];                 // broadcast
        const float4* kvrow = (const float4*)&KVl[dd * 64 + qg * 16];  // <=2-way
        float4 v0 = kvrow[0], v1 = kvrow[1], v2 = kvrow[2], v3 = kvrow[3];
        acc[0]  += qd * v0.x; acc[1]  += qd * v0.y; acc[2]  += qd * v0.z; acc[3]  += qd * v0.w;
        acc[4]  += qd * v1.x; acc[5]  += qd * v1.y; acc[6]  += qd * v1.z; acc[7]  += qd * v1.w;
        acc[8]  += qd * v2.x; acc[9]  += qd * v2.y; acc[10] += qd * v2.z; acc[11] += qd * v2.w;
        acc[12] += qd * v3.x; acc[13] += qd * v3.y; acc[14] += qd * v3.z; acc[15] += qd * v3.w;
    }
    float z = 1.f / (den + 1e-6f);
    float* orow = out + ((size_t)((n * LQ + l0 + r) * NH + h)) * DD + qg * 16;
    *(float4*)&orow[0]  = make_float4(acc[0]  * z, acc[1]  * z, acc[2]  * z, acc[3]  * z);
    *(float4*)&orow[4]  = make_float4(acc[4]  * z, acc[5]  * z, acc[6]  * z, acc[7]  * z);
    *(float4*)&orow[8]  = make_float4(acc[8]  * z, acc[9]  * z, acc[10] * z, acc[11] * z);
    *(float4*)&orow[12] = make_float4(acc[12] * z, acc[13] * z, acc[14] * z, acc[15] * z);
}

extern "C" void kernel_launch(void* const* d_in, const int* in_sizes, int n_in,
                              void* d_out, int out_size, void* d_ws, size_t ws_size,
                              hipStream_t stream) {
    const float* Q   = (const float*)d_in[0];
    const float* K   = (const float*)d_in[1];
    const float* V   = (const float*)d_in[2];
    const float* qm  = (const float*)d_in[3];
    const float* kvm = (const float*)d_in[4];
    float* out = (float*)d_out;

    // pick chunk count that fits the workspace: (CH partials + 1 final) * 64 * 4160 floats
    int CH = 16;
    while (CH > 1 && (size_t)(CH + 1) * NPAIR * KVSZ * sizeof(float) > ws_size) CH >>= 1;
    int SC = SK / CH;

    float* partial = (float*)d_ws;
    float* kvf = partial + (size_t)CH * NPAIR * KVSZ;

    kv_partial_kernel<<<dim3(NPAIR * CH), dim3(256), 0, stream>>>(K, V, kvm, partial, CH, SC);
    kv_reduce_kernel<<<dim3((NPAIR * KVSZ + 255) / 256), dim3(256), 0, stream>>>(partial, kvf, CH);
    attn_out_kernel<<<dim3(NPAIR * 64), dim3(256), 0, stream>>>(Q, qm, kvf, out);
}